// Round 17
// baseline (1070.480 us; speedup 1.0000x reference)
//
#include <hip/hip_runtime.h>

typedef _Float16 half8 __attribute__((ext_vector_type(8)));
typedef float f32x4 __attribute__((ext_vector_type(4)));

#define TT 48
#define BT 32
#define NSEQ 16384
#define NGRP (NSEQ / BT)           // 512 groups
#define NPAIR (NGRP / 2)           // 256 group-pairs (one per block)
#define NTHR 512
#define H0_SLICE (TT * BT * 136)   // f16 elems per group slice (417792 B)
#define GOFF_A 7424                // group B offset in A panel (elems)
#define GOFF_G 8976                // group B offset in gates (floats)

// h0w layout per slice: [t][d][b][j], stride per t = 4352 f16
struct __align__(16) Smem {
  float gates[2 * 272 * 33];      // 71808 B  [group][gate][batch(+pad)]
  _Float16 A[2 * 32 * 232];       // 29696 B  A panels [group][32][AW]
  union {
    _Float16 bx[7 * 64 * 8];      //  7168 B  LDS B-fragments for tile 16
    float ysc[2 * 32 * 5];        //  FC combine scratch (after passes)
  } u;
  float fcwt[2][340];             //  2720 B  staged fcw slice (shared by groups)
};                                // 111392 B dynamic LDS

__device__ __forceinline__ float fast_rcp(float v) { return __builtin_amdgcn_rcpf(v); }
__device__ __forceinline__ float sigm(float v)  { return fast_rcp(1.f + __expf(-v)); }
__device__ __forceinline__ float tanh_s(float v){ return 1.f - 2.f * fast_rcp(1.f + __expf(2.f * v)); }

// elementwise cell update for one group (b-uniform ownership; static indexing)
template <int LAYER>
__device__ __forceinline__ void cell_update(float* gates, _Float16* A,
    _Float16* h0w, const float* fcwt_cur, float (&cst)[5], float (&yk)[5],
    const int tid, const int t, const int d)
{
  constexpr int AW   = LAYER ? 232 : 136;
  constexpr int HOFF = LAYER ? 136 : 34;
  const int b = tid >> 4, jb = tid & 15;
  #pragma unroll
  for (int q = 0; q < 5; ++q) {
    if (q < 4 || jb < 4) {
      const int j = (q < 4) ? (jb + 16 * q) : (64 + jb);
      const int gq = j * 33 + b;
      const float gi = gates[gq];
      const float gf = gates[gq + 2244];
      const float gg = gates[gq + 4488];
      const float go = gates[gq + 6732];
      const float ii = sigm(gi), ff = sigm(gf), g2 = tanh_s(gg), oo = sigm(go);
      const float cc = ff * cst[q] + ii * g2;
      cst[q] = cc;
      const float h = oo * tanh_s(cc);
      const _Float16 h16 = (_Float16)h;
      A[b * AW + HOFF + j] = h16;
      if constexpr (LAYER == 0) {
        h0w[t * 4352 + d * 2176 + b * 68 + j] = h16;
      } else {
        #pragma unroll
        for (int k = 0; k < 5; ++k) yk[k] += h * fcwt_cur[k * 68 + j];
      }
    }
  }
}

// One (layer, dir) recurrence over TWO groups (A,B), all 8 waves.
// Wave w owns reg B-tiles {2w,2w+1}; tile 16 via LDS bx (wave 0). Bf shared by groups.
template <int LAYER>
__device__ __forceinline__ void pass_lstm(Smem& s, const int d,
    const float* __restrict__ Wih, const float* __restrict__ Whh,
    const float* __restrict__ bih, const float* __restrict__ bhh,
    const float* __restrict__ xgA, const float* __restrict__ xgB,
    const float* __restrict__ fcw,
    _Float16* __restrict__ h0wA, _Float16* __restrict__ h0wB,
    float (&cstA)[5], float (&cstB)[5], float (&ykA)[5], float (&ykB)[5])
{
  constexpr int AW    = LAYER ? 232 : 136;
  constexpr int KS    = LAYER ? 7 : 4;
  constexpr int INW   = LAYER ? 136 : 34;
  constexpr int BIASC = INW + 68;
  const int tid = threadIdx.x;
  const int ln = tid & 63, wid = tid >> 6;
  const int lr = ln & 15, lq = ln >> 4;

  float* gates = s.gates;
  _Float16* A  = s.A;

  // ---- reg B fragments: 2 tiles per wave (shared across both groups) ----
  half8 Bf[2][KS];
  #pragma unroll
  for (int i = 0; i < 2; ++i) {
    const int g = (wid * 2 + i) * 16 + lr;
    #pragma unroll
    for (int kk = 0; kk < KS; ++kk) {
      half8 v;
      #pragma unroll
      for (int j = 0; j < 8; ++j) {
        const int k = kk * 32 + lq * 8 + j;
        float wv = 0.f;
        if (k < INW) wv = Wih[g * INW + k];
        else if (k < BIASC) wv = Whh[g * 68 + (k - INW)];
        else if (k == BIASC) wv = bih[g] + bhh[g];
        v[j] = (_Float16)wv;
      }
      Bf[i][kk] = v;
    }
  }
  // ---- LDS B fragments for tile 16 ----
  if (tid < KS * 64) {
    const int kk = tid >> 6, l2 = tid & 63;
    const int g = 256 + (l2 & 15);
    half8 v;
    #pragma unroll
    for (int j = 0; j < 8; ++j) {
      const int k = kk * 32 + (l2 >> 4) * 8 + j;
      float wv = 0.f;
      if (k < INW) wv = Wih[g * INW + k];
      else if (k < BIASC) wv = Whh[g * 68 + (k - INW)];
      else if (k == BIASC) wv = bih[g] + bhh[g];
      v[j] = (_Float16)wv;
    }
    *(half8*)&s.u.bx[tid * 8] = v;
  }

  #pragma unroll
  for (int q = 0; q < 5; ++q) { cstA[q] = 0.f; cstB[q] = 0.f; }

  // ---- staging offsets (t-independent, group-local) ----
  int sgo0, sao0, sgo1, sao1, sgo2, sao2;
  if constexpr (LAYER == 0) {
    { const int b = tid / 34, i = tid % 34;
      sgo0 = b * (TT * 34) + i;  sao0 = b * 136 + i; }
    { const int t1 = tid + 512, b = t1 / 34, i = t1 % 34;
      sgo1 = b * (TT * 34) + i;  sao1 = b * 136 + i; }
    { const int t2 = (tid < 64) ? (tid + 1024) : 1024, b = t2 / 34, i = t2 % 34;
      sgo2 = b * (TT * 34) + i;  sao2 = b * 136 + i; }
  } else {
    { const int dd = tid / 544, r = tid % 544, b = r / 17, c = r % 17;
      sgo0 = dd * 2176 + b * 68 + c * 4;  sao0 = b * 232 + dd * 68 + c * 4; }
    { const int t1 = tid + 512, dd = t1 / 544, r = t1 % 544, b = r / 17, c = r % 17;
      sgo1 = dd * 2176 + b * 68 + c * 4;  sao1 = b * 232 + dd * 68 + c * 4; }
    { const int t2 = (tid < 64) ? (tid + 1024) : 1024, dd = t2 / 544, r = t2 % 544,
        b = r / 17, c = r % 17;
      sgo2 = dd * 2176 + b * 68 + c * 4;  sao2 = b * 232 + dd * 68 + c * 4; }
  }
  int fk2 = 0, fj = 0;
  if constexpr (LAYER) { if (tid < 340) { fk2 = tid / 68; fj = tid % 68; } }

  // ---- prologue: zero both A panels (1856 uint4), bias cols, stage step 0 ----
  {
    const uint4 zz = {0, 0, 0, 0};
    ((uint4*)A)[tid] = zz;
    ((uint4*)A)[512 + tid] = zz;
    ((uint4*)A)[1024 + tid] = zz;
    if (tid < 320) ((uint4*)A)[1536 + tid] = zz;
  }
  __syncthreads();
  if (tid < 64) A[(tid >> 5) * GOFF_A + (tid & 31) * AW + BIASC] = (_Float16)1.f;
  const int t0 = d ? (TT - 1) : 0;
  if constexpr (LAYER == 0) {
    A[sao0] = (_Float16)xgA[sgo0 + t0 * 34];
    A[sao1] = (_Float16)xgA[sgo1 + t0 * 34];
    if (tid < 64) A[sao2] = (_Float16)xgA[sgo2 + t0 * 34];
    A[GOFF_A + sao0] = (_Float16)xgB[sgo0 + t0 * 34];
    A[GOFF_A + sao1] = (_Float16)xgB[sgo1 + t0 * 34];
    if (tid < 64) A[GOFF_A + sao2] = (_Float16)xgB[sgo2 + t0 * 34];
  } else {
    *(uint2*)&A[sao0] = *(const uint2*)&h0wA[sgo0 + t0 * 4352];
    *(uint2*)&A[sao1] = *(const uint2*)&h0wA[sgo1 + t0 * 4352];
    if (tid < 64) *(uint2*)&A[sao2] = *(const uint2*)&h0wA[sgo2 + t0 * 4352];
    *(uint2*)&A[GOFF_A + sao0] = *(const uint2*)&h0wB[sgo0 + t0 * 4352];
    *(uint2*)&A[GOFF_A + sao1] = *(const uint2*)&h0wB[sgo1 + t0 * 4352];
    if (tid < 64) *(uint2*)&A[GOFF_A + sao2] = *(const uint2*)&h0wB[sgo2 + t0 * 4352];
    if (tid < 340) s.fcwt[0][tid] = fcw[fk2 * 6528 + t0 * 136 + d * 68 + fj];
  }
  __syncthreads();

  #pragma unroll 1
  for (int st = 0; st < TT; ++st) {
    const int t  = d ? (TT - 1 - st) : st;
    const int tn = d ? (t - 1) : (t + 1);

    // ---- prefetch next step's staging for both groups ----
    float xpA0 = 0.f, xpA1 = 0.f, xpA2 = 0.f, xpB0 = 0.f, xpB1 = 0.f, xpB2 = 0.f, fwp = 0.f;
    uint2 hpA0 = {0,0}, hpA1 = {0,0}, hpA2 = {0,0}, hpB0 = {0,0}, hpB1 = {0,0}, hpB2 = {0,0};
    if (st < TT - 1) {
      if constexpr (LAYER == 0) {
        xpA0 = xgA[sgo0 + tn * 34];  xpB0 = xgB[sgo0 + tn * 34];
        xpA1 = xgA[sgo1 + tn * 34];  xpB1 = xgB[sgo1 + tn * 34];
        if (tid < 64) { xpA2 = xgA[sgo2 + tn * 34];  xpB2 = xgB[sgo2 + tn * 34]; }
      } else {
        hpA0 = *(const uint2*)&h0wA[sgo0 + tn * 4352];
        hpB0 = *(const uint2*)&h0wB[sgo0 + tn * 4352];
        hpA1 = *(const uint2*)&h0wA[sgo1 + tn * 4352];
        hpB1 = *(const uint2*)&h0wB[sgo1 + tn * 4352];
        if (tid < 64) {
          hpA2 = *(const uint2*)&h0wA[sgo2 + tn * 4352];
          hpB2 = *(const uint2*)&h0wB[sgo2 + tn * 4352];
        }
        if (tid < 340) fwp = fcw[fk2 * 6528 + tn * 136 + d * 68 + fj];
      }
    }

    // ---- MFMA: both groups per kk (4-6 independent chains); halves sequential ----
    #pragma unroll
    for (int hf = 0; hf < 2; ++hf) {
      f32x4 aA0 = {0,0,0,0}, aA1 = {0,0,0,0}, aA2 = {0,0,0,0};
      f32x4 aB0 = {0,0,0,0}, aB1 = {0,0,0,0}, aB2 = {0,0,0,0};
      #pragma unroll
      for (int kk = 0; kk < KS; ++kk) {
        const half8 avA = *(const half8*)&A[(lr + 16 * hf) * AW + kk * 32 + lq * 8];
        const half8 avB = *(const half8*)&A[GOFF_A + (lr + 16 * hf) * AW + kk * 32 + lq * 8];
        aA0 = __builtin_amdgcn_mfma_f32_16x16x32_f16(avA, Bf[0][kk], aA0, 0, 0, 0);
        aB0 = __builtin_amdgcn_mfma_f32_16x16x32_f16(avB, Bf[0][kk], aB0, 0, 0, 0);
        aA1 = __builtin_amdgcn_mfma_f32_16x16x32_f16(avA, Bf[1][kk], aA1, 0, 0, 0);
        aB1 = __builtin_amdgcn_mfma_f32_16x16x32_f16(avB, Bf[1][kk], aB1, 0, 0, 0);
        if (wid == 0) {
          const half8 bb = *(const half8*)&s.u.bx[(kk * 64 + ln) * 8];
          aA2 = __builtin_amdgcn_mfma_f32_16x16x32_f16(avA, bb, aA2, 0, 0, 0);
          aB2 = __builtin_amdgcn_mfma_f32_16x16x32_f16(avB, bb, aB2, 0, 0, 0);
        }
      }
      const int g0 = (wid * 2) * 16 + lr;
      #pragma unroll
      for (int r = 0; r < 4; ++r) {
        gates[g0 * 33 + 16 * hf + lq * 4 + r]                 = aA0[r];
        gates[(g0 + 16) * 33 + 16 * hf + lq * 4 + r]          = aA1[r];
        gates[GOFF_G + g0 * 33 + 16 * hf + lq * 4 + r]        = aB0[r];
        gates[GOFF_G + (g0 + 16) * 33 + 16 * hf + lq * 4 + r] = aB1[r];
      }
      if (wid == 0) {
        #pragma unroll
        for (int r = 0; r < 4; ++r) {
          gates[(256 + lr) * 33 + 16 * hf + lq * 4 + r]          = aA2[r];
          gates[GOFF_G + (256 + lr) * 33 + 16 * hf + lq * 4 + r] = aB2[r];
        }
      }
    }
    __syncthreads();

    // ---- elementwise: group A then group B ----
    cell_update<LAYER>(gates, A, h0wA, s.fcwt[st & 1], cstA, ykA, tid, t, d);
    cell_update<LAYER>(gates + GOFF_G, A + GOFF_A, h0wB, s.fcwt[st & 1], cstB, ykB, tid, t, d);

    // ---- staging writes for next step ----
    if (st < TT - 1) {
      if constexpr (LAYER == 0) {
        A[sao0] = (_Float16)xpA0;  A[GOFF_A + sao0] = (_Float16)xpB0;
        A[sao1] = (_Float16)xpA1;  A[GOFF_A + sao1] = (_Float16)xpB1;
        if (tid < 64) { A[sao2] = (_Float16)xpA2;  A[GOFF_A + sao2] = (_Float16)xpB2; }
      } else {
        *(uint2*)&A[sao0] = hpA0;  *(uint2*)&A[GOFF_A + sao0] = hpB0;
        *(uint2*)&A[sao1] = hpA1;  *(uint2*)&A[GOFF_A + sao1] = hpB1;
        if (tid < 64) { *(uint2*)&A[sao2] = hpA2;  *(uint2*)&A[GOFF_A + sao2] = hpB2; }
        if (tid < 340) s.fcwt[(st + 1) & 1][tid] = fwp;
      }
    }
    __syncthreads();
  }
}

__global__ __attribute__((amdgpu_flat_work_group_size(NTHR, NTHR)))
void lstm_fc_kernel(
    const float* __restrict__ x,
    const float* __restrict__ Wih0f, const float* __restrict__ Whh0f,
    const float* __restrict__ bih0f, const float* __restrict__ bhh0f,
    const float* __restrict__ Wih0b, const float* __restrict__ Whh0b,
    const float* __restrict__ bih0b, const float* __restrict__ bhh0b,
    const float* __restrict__ Wih1f, const float* __restrict__ Whh1f,
    const float* __restrict__ bih1f, const float* __restrict__ bhh1f,
    const float* __restrict__ Wih1b, const float* __restrict__ Whh1b,
    const float* __restrict__ bih1b, const float* __restrict__ bhh1b,
    const float* __restrict__ fcw, const float* __restrict__ fcb,
    float* __restrict__ out, _Float16* __restrict__ ws)
{
  extern __shared__ char smem_raw[];
  Smem& s = *reinterpret_cast<Smem*>(smem_raw);
  const int tid = threadIdx.x;
  _Float16* h0wA = ws + (size_t)blockIdx.x * (2 * H0_SLICE);
  _Float16* h0wB = h0wA + H0_SLICE;

  for (int p = blockIdx.x; p < NPAIR; p += gridDim.x) {
    const float* xgA = x + (size_t)(2 * p) * (BT * TT * 34);
    const float* xgB = xgA + (size_t)(BT * TT * 34);
    float cstA[5], cstB[5];
    float ykA[5] = {0,0,0,0,0}, ykB[5] = {0,0,0,0,0};

    pass_lstm<0>(s, 0, Wih0f, Whh0f, bih0f, bhh0f, xgA, xgB, nullptr,
                 h0wA, h0wB, cstA, cstB, ykA, ykB);
    pass_lstm<0>(s, 1, Wih0b, Whh0b, bih0b, bhh0b, xgA, xgB, nullptr,
                 h0wA, h0wB, cstA, cstB, ykA, ykB);
    pass_lstm<1>(s, 0, Wih1f, Whh1f, bih1f, bhh1f, xgA, xgB, fcw,
                 h0wA, h0wB, cstA, cstB, ykA, ykB);
    pass_lstm<1>(s, 1, Wih1b, Whh1b, bih1b, bhh1b, xgA, xgB, fcw,
                 h0wA, h0wB, cstA, cstB, ykA, ykB);

    // ---- FC epilogue: butterfly over 16 threads sharing b, both groups ----
    #pragma unroll
    for (int m = 1; m < 16; m <<= 1) {
      #pragma unroll
      for (int k = 0; k < 5; ++k) {
        ykA[k] += __shfl_xor(ykA[k], m, 64);
        ykB[k] += __shfl_xor(ykB[k], m, 64);
      }
    }
    __syncthreads();   // all passes done before overwriting bx-union with ysc
    if ((tid & 15) == 0) {
      const int b = tid >> 4;
      #pragma unroll
      for (int k = 0; k < 5; ++k) {
        s.u.ysc[b * 5 + k]       = ykA[k];
        s.u.ysc[160 + b * 5 + k] = ykB[k];
      }
    }
    __syncthreads();
    if (tid < 320) {
      const int grpg = tid / 160, rem = tid - grpg * 160;
      const int k = rem % 5;
      out[(size_t)((2 * p + grpg) * BT) * 5 + rem] = s.u.ysc[grpg * 160 + rem] + fcb[k];
    }
    __syncthreads();
  }
}

extern "C" void kernel_launch(void* const* d_in, const int* in_sizes, int n_in,
                              void* d_out, int out_size, void* d_ws, size_t ws_size,
                              hipStream_t stream) {
  (void)in_sizes; (void)n_in; (void)out_size;
  static_assert(sizeof(Smem) <= 160 * 1024, "LDS overflow");
  hipFuncSetAttribute((const void*)lstm_fc_kernel,
                      hipFuncAttributeMaxDynamicSharedMemorySize, (int)sizeof(Smem));

  const float* x     = (const float*)d_in[0];
  const float* Wih0f = (const float*)d_in[1];
  const float* Whh0f = (const float*)d_in[2];
  const float* bih0f = (const float*)d_in[3];
  const float* bhh0f = (const float*)d_in[4];
  const float* Wih0b = (const float*)d_in[5];
  const float* Whh0b = (const float*)d_in[6];
  const float* bih0b = (const float*)d_in[7];
  const float* bhh0b = (const float*)d_in[8];
  const float* Wih1f = (const float*)d_in[9];
  const float* Whh1f = (const float*)d_in[10];
  const float* bih1f = (const float*)d_in[11];
  const float* bhh1f = (const float*)d_in[12];
  const float* Wih1b = (const float*)d_in[13];
  const float* Whh1b = (const float*)d_in[14];
  const float* bih1b = (const float*)d_in[15];
  const float* bhh1b = (const float*)d_in[16];
  const float* fcw   = (const float*)d_in[17];
  const float* fcb   = (const float*)d_in[18];
  float* out = (float*)d_out;

  // two h0 slices per block (835584 B); degrade grid if ws is small
  long long slices = (long long)(ws_size / (size_t)(2 * H0_SLICE * 2));
  int grid = (int)(slices < 1 ? 1 : slices);
  if (grid > NPAIR) grid = NPAIR;

  lstm_fc_kernel<<<dim3(grid), dim3(NTHR), sizeof(Smem), stream>>>(x,
      Wih0f, Whh0f, bih0f, bhh0f, Wih0b, Whh0b, bih0b, bhh0b,
      Wih1f, Whh1f, bih1f, bhh1f, Wih1b, Whh1b, bih1b, bhh1b,
      fcw, fcb, out, (_Float16*)d_ws);
}

// Round 18
// 934.351 us; speedup vs baseline: 1.1457x; 1.1457x over previous
//
#include <hip/hip_runtime.h>

typedef _Float16 half8 __attribute__((ext_vector_type(8)));
typedef float f32x4 __attribute__((ext_vector_type(4)));

#define TT 48
#define BT 32
#define NSEQ 16384
#define NGRP (NSEQ / BT)           // 512 groups
#define NTHR 512
#define MAXGRID 512
#define H0_SLICE (TT * BT * 136)   // f16 elems per block ws slice (417792 B)

// h0w layout: [t][d][b][j], stride per t = 4352 f16
struct __align__(16) Smem {
  float gates[272 * 33];        // 35904 B  [gate][batch(+pad)]
  _Float16 A[32 * 232];         // 14848 B  A panel (L0 view: [32][136])
  union {
    _Float16 bx[7 * 64 * 8];    //  7168 B  LDS B-fragments for tile 16 (during passes)
    float ysc[160];             //  FC combine scratch (after passes)
  } u;
  float fcwt[2][340];           //  2720 B  staged fcw slice, double-buffered (L1 only)
};                              // 60640 B static LDS

__device__ __forceinline__ float fast_rcp(float v) { return __builtin_amdgcn_rcpf(v); }
__device__ __forceinline__ float sigm(float v)  { return fast_rcp(1.f + __expf(-v)); }
__device__ __forceinline__ float tanh_s(float v){ return 1.f - 2.f * fast_rcp(1.f + __expf(2.f * v)); }

// One (layer, dir) recurrence over 32 sequences, all 8 waves.
// Wave w owns reg B-tiles {2w, 2w+1}; tile 16 via LDS bx: wave 0 lo-half, wave 1 hi-half.
template <int LAYER>
__device__ __forceinline__ void pass_lstm(Smem& s, const int d,
    const float* __restrict__ Wih, const float* __restrict__ Whh,
    const float* __restrict__ bih, const float* __restrict__ bhh,
    const float* __restrict__ xg,  const float* __restrict__ fcw,
    _Float16* __restrict__ h0w, float (&yk)[5])
{
  constexpr int AW    = LAYER ? 232 : 136;  // A row stride (f16)
  constexpr int KS    = LAYER ? 7 : 4;      // K chunks of 32 (224 / 128)
  constexpr int INW   = LAYER ? 136 : 34;   // non-recurrent width
  constexpr int BIASC = INW + 68;           // bias-one column (204 / 102)
  constexpr int HOFF  = LAYER ? 136 : 34;   // h slot base in A row

  const int tid = threadIdx.x;
  const int ln = tid & 63, wid = tid >> 6;
  const int lr = ln & 15, lq = ln >> 4;

  float* gates = s.gates;
  _Float16* A  = s.A;

  // ---- reg B fragments: 2 tiles per wave ----
  half8 Bf[2][KS];
  #pragma unroll
  for (int i = 0; i < 2; ++i) {
    const int g = (wid * 2 + i) * 16 + lr;
    #pragma unroll
    for (int kk = 0; kk < KS; ++kk) {
      half8 v;
      #pragma unroll
      for (int j = 0; j < 8; ++j) {
        const int k = kk * 32 + lq * 8 + j;
        float wv = 0.f;
        if (k < INW) wv = Wih[g * INW + k];
        else if (k < BIASC) wv = Whh[g * 68 + (k - INW)];
        else if (k == BIASC) wv = bih[g] + bhh[g];
        v[j] = (_Float16)wv;
      }
      Bf[i][kk] = v;
    }
  }
  // ---- LDS B fragments for tile 16 ----
  if (tid < KS * 64) {
    const int kk = tid >> 6, l2 = tid & 63;
    const int g = 256 + (l2 & 15);
    half8 v;
    #pragma unroll
    for (int j = 0; j < 8; ++j) {
      const int k = kk * 32 + (l2 >> 4) * 8 + j;
      float wv = 0.f;
      if (k < INW) wv = Wih[g * INW + k];
      else if (k < BIASC) wv = Whh[g * 68 + (k - INW)];
      else if (k == BIASC) wv = bih[g] + bhh[g];
      v[j] = (_Float16)wv;
    }
    *(half8*)&s.u.bx[tid * 8] = v;
  }

  float cst[5];
  #pragma unroll
  for (int q = 0; q < 5; ++q) cst[q] = 0.f;

  // ---- staging offsets (t-independent); 1088 tasks = 2*512 + 64 extras ----
  int sgo0, sao0, sgo1, sao1, sgo2, sao2;
  if constexpr (LAYER == 0) {
    { const int b = tid / 34, i = tid % 34;
      sgo0 = b * (TT * 34) + i;  sao0 = b * 136 + i; }
    { const int t1 = tid + 512, b = t1 / 34, i = t1 % 34;
      sgo1 = b * (TT * 34) + i;  sao1 = b * 136 + i; }
    { const int t2 = (tid < 64) ? (tid + 1024) : 1024, b = t2 / 34, i = t2 % 34;
      sgo2 = b * (TT * 34) + i;  sao2 = b * 136 + i; }
  } else {
    { const int dd = tid / 544, r = tid % 544, b = r / 17, c = r % 17;
      sgo0 = dd * 2176 + b * 68 + c * 4;  sao0 = b * 232 + dd * 68 + c * 4; }
    { const int t1 = tid + 512, dd = t1 / 544, r = t1 % 544, b = r / 17, c = r % 17;
      sgo1 = dd * 2176 + b * 68 + c * 4;  sao1 = b * 232 + dd * 68 + c * 4; }
    { const int t2 = (tid < 64) ? (tid + 1024) : 1024, dd = t2 / 544, r = t2 % 544,
        b = r / 17, c = r % 17;
      sgo2 = dd * 2176 + b * 68 + c * 4;  sao2 = b * 232 + dd * 68 + c * 4; }
  }
  int fk2 = 0, fj = 0;
  if constexpr (LAYER) { if (tid < 340) { fk2 = tid / 68; fj = tid % 68; } }

  // ---- prologue: zero A (928 uint4), bias col, stage step 0 ----
  {
    const uint4 zz = {0, 0, 0, 0};
    ((uint4*)A)[tid] = zz;
    if (tid < 416) ((uint4*)A)[512 + tid] = zz;
  }
  __syncthreads();
  if (tid < 32) A[tid * AW + BIASC] = (_Float16)1.f;
  const int t0 = d ? (TT - 1) : 0;
  if constexpr (LAYER == 0) {
    A[sao0] = (_Float16)xg[sgo0 + t0 * 34];
    A[sao1] = (_Float16)xg[sgo1 + t0 * 34];
    if (tid < 64) A[sao2] = (_Float16)xg[sgo2 + t0 * 34];
  } else {
    *(uint2*)&A[sao0] = *(const uint2*)&h0w[sgo0 + t0 * 4352];
    *(uint2*)&A[sao1] = *(const uint2*)&h0w[sgo1 + t0 * 4352];
    if (tid < 64) *(uint2*)&A[sao2] = *(const uint2*)&h0w[sgo2 + t0 * 4352];
    if (tid < 340) s.fcwt[0][tid] = fcw[fk2 * 6528 + t0 * 136 + d * 68 + fj];
  }
  __syncthreads();

  #pragma unroll 1
  for (int st = 0; st < TT; ++st) {
    const int t  = d ? (TT - 1 - st) : st;
    const int tn = d ? (t - 1) : (t + 1);

    // ---- prefetch next step's staging into registers ----
    float xp0 = 0.f, xp1 = 0.f, xp2 = 0.f, fwp = 0.f;
    uint2 hp0 = {0, 0}, hp1 = {0, 0}, hp2 = {0, 0};
    if (st < TT - 1) {
      if constexpr (LAYER == 0) {
        xp0 = xg[sgo0 + tn * 34];
        xp1 = xg[sgo1 + tn * 34];
        if (tid < 64) xp2 = xg[sgo2 + tn * 34];
      } else {
        hp0 = *(const uint2*)&h0w[sgo0 + tn * 4352];
        hp1 = *(const uint2*)&h0w[sgo1 + tn * 4352];
        if (tid < 64) hp2 = *(const uint2*)&h0w[sgo2 + tn * 4352];
        if (tid < 340) fwp = fcw[fk2 * 6528 + tn * 136 + d * 68 + fj];
      }
    }

    // ---- MFMA: gates(32x272) = A(32xK).B(Kx272); concurrent lo/hi halves ----
    f32x4 aL0 = {0.f,0.f,0.f,0.f}, aH0 = {0.f,0.f,0.f,0.f};
    f32x4 aL1 = {0.f,0.f,0.f,0.f}, aH1 = {0.f,0.f,0.f,0.f};
    f32x4 a2  = {0.f,0.f,0.f,0.f};   // tile 16: wave 0 -> lo half, wave 1 -> hi half
    #pragma unroll
    for (int kk = 0; kk < KS; ++kk) {
      const half8 alo = *(const half8*)&A[lr * AW + kk * 32 + lq * 8];
      const half8 ahi = *(const half8*)&A[(lr + 16) * AW + kk * 32 + lq * 8];
      aL0 = __builtin_amdgcn_mfma_f32_16x16x32_f16(alo, Bf[0][kk], aL0, 0, 0, 0);
      aH0 = __builtin_amdgcn_mfma_f32_16x16x32_f16(ahi, Bf[0][kk], aH0, 0, 0, 0);
      aL1 = __builtin_amdgcn_mfma_f32_16x16x32_f16(alo, Bf[1][kk], aL1, 0, 0, 0);
      aH1 = __builtin_amdgcn_mfma_f32_16x16x32_f16(ahi, Bf[1][kk], aH1, 0, 0, 0);
      if (wid < 2) {
        const half8 bb = *(const half8*)&s.u.bx[(kk * 64 + ln) * 8];
        const half8 av = (wid == 0) ? alo : ahi;
        a2 = __builtin_amdgcn_mfma_f32_16x16x32_f16(av, bb, a2, 0, 0, 0);
      }
    }
    // C/D: col = lr (gate within tile), row = lq*4+r (batch; +16 for hi tile)
    {
      const int g0 = (wid * 2) * 16 + lr;
      #pragma unroll
      for (int r = 0; r < 4; ++r) {
        gates[g0 * 33 + lq * 4 + r]              = aL0[r];
        gates[g0 * 33 + 16 + lq * 4 + r]         = aH0[r];
        gates[(g0 + 16) * 33 + lq * 4 + r]       = aL1[r];
        gates[(g0 + 16) * 33 + 16 + lq * 4 + r]  = aH1[r];
      }
      if (wid < 2) {
        #pragma unroll
        for (int r = 0; r < 4; ++r)
          gates[(256 + lr) * 33 + 16 * wid + lq * 4 + r] = a2[r];
      }
    }
    __syncthreads();

    // ---- elementwise cell update: b-uniform ownership ----
    {
      const int b = tid >> 4, jb = tid & 15;
      #pragma unroll
      for (int q = 0; q < 5; ++q) {
        if (q < 4 || jb < 4) {
          const int j = (q < 4) ? (jb + 16 * q) : (64 + jb);
          const int gq = j * 33 + b;
          const float gi = gates[gq];
          const float gf = gates[gq + 2244];    // (68+j)*33+b
          const float gg = gates[gq + 4488];
          const float go = gates[gq + 6732];
          const float ii = sigm(gi), ff = sigm(gf), g2 = tanh_s(gg), oo = sigm(go);
          const float cc = ff * cst[q] + ii * g2;
          cst[q] = cc;
          const float h = oo * tanh_s(cc);
          const _Float16 h16 = (_Float16)h;
          A[b * AW + HOFF + j] = h16;
          if constexpr (LAYER == 0) {
            h0w[t * 4352 + d * 2176 + b * 68 + j] = h16;
          } else {
            #pragma unroll
            for (int k = 0; k < 5; ++k) yk[k] += h * s.fcwt[st & 1][k * 68 + j];
          }
        }
      }
    }
    // ---- staging writes for next step ----
    if (st < TT - 1) {
      if constexpr (LAYER == 0) {
        A[sao0] = (_Float16)xp0;
        A[sao1] = (_Float16)xp1;
        if (tid < 64) A[sao2] = (_Float16)xp2;
      } else {
        *(uint2*)&A[sao0] = hp0;
        *(uint2*)&A[sao1] = hp1;
        if (tid < 64) *(uint2*)&A[sao2] = hp2;
        if (tid < 340) s.fcwt[(st + 1) & 1][tid] = fwp;
      }
    }
    __syncthreads();
  }
}

__global__ __attribute__((amdgpu_flat_work_group_size(NTHR, NTHR)))
void lstm_fc_kernel(
    const float* __restrict__ x,
    const float* __restrict__ Wih0f, const float* __restrict__ Whh0f,
    const float* __restrict__ bih0f, const float* __restrict__ bhh0f,
    const float* __restrict__ Wih0b, const float* __restrict__ Whh0b,
    const float* __restrict__ bih0b, const float* __restrict__ bhh0b,
    const float* __restrict__ Wih1f, const float* __restrict__ Whh1f,
    const float* __restrict__ bih1f, const float* __restrict__ bhh1f,
    const float* __restrict__ Wih1b, const float* __restrict__ Whh1b,
    const float* __restrict__ bih1b, const float* __restrict__ bhh1b,
    const float* __restrict__ fcw, const float* __restrict__ fcb,
    float* __restrict__ out, _Float16* __restrict__ ws)
{
  __shared__ Smem s;
  const int tid = threadIdx.x;
  _Float16* h0w = ws + (size_t)blockIdx.x * H0_SLICE;

  for (int grp = blockIdx.x; grp < NGRP; grp += gridDim.x) {
    const float* xg = x + (size_t)grp * (BT * TT * 34);
    float yk[5] = {0.f, 0.f, 0.f, 0.f, 0.f};

    pass_lstm<0>(s, 0, Wih0f, Whh0f, bih0f, bhh0f, xg, nullptr, h0w, yk);
    pass_lstm<0>(s, 1, Wih0b, Whh0b, bih0b, bhh0b, xg, nullptr, h0w, yk);
    pass_lstm<1>(s, 0, Wih1f, Whh1f, bih1f, bhh1f, nullptr, fcw, h0w, yk);
    pass_lstm<1>(s, 1, Wih1b, Whh1b, bih1b, bhh1b, nullptr, fcw, h0w, yk);

    // ---- FC epilogue: butterfly over the 16 threads sharing b, then combine ----
    #pragma unroll
    for (int m = 1; m < 16; m <<= 1) {
      #pragma unroll
      for (int k = 0; k < 5; ++k) yk[k] += __shfl_xor(yk[k], m, 64);
    }
    __syncthreads();   // all passes done before overwriting bx-union with ysc
    if ((tid & 15) == 0) {
      #pragma unroll
      for (int k = 0; k < 5; ++k) s.u.ysc[(tid >> 4) * 5 + k] = yk[k];
    }
    __syncthreads();
    if (tid < BT * 5) {
      const int k = tid % 5;
      out[(size_t)(grp * BT) * 5 + tid] = s.u.ysc[tid] + fcb[k];
    }
    __syncthreads();
  }
}

extern "C" void kernel_launch(void* const* d_in, const int* in_sizes, int n_in,
                              void* d_out, int out_size, void* d_ws, size_t ws_size,
                              hipStream_t stream) {
  (void)in_sizes; (void)n_in; (void)out_size;
  static_assert(sizeof(Smem) <= 60 * 1024, "LDS budget");

  const float* x     = (const float*)d_in[0];
  const float* Wih0f = (const float*)d_in[1];
  const float* Whh0f = (const float*)d_in[2];
  const float* bih0f = (const float*)d_in[3];
  const float* bhh0f = (const float*)d_in[4];
  const float* Wih0b = (const float*)d_in[5];
  const float* Whh0b = (const float*)d_in[6];
  const float* bih0b = (const float*)d_in[7];
  const float* bhh0b = (const float*)d_in[8];
  const float* Wih1f = (const float*)d_in[9];
  const float* Whh1f = (const float*)d_in[10];
  const float* bih1f = (const float*)d_in[11];
  const float* bhh1f = (const float*)d_in[12];
  const float* Wih1b = (const float*)d_in[13];
  const float* Whh1b = (const float*)d_in[14];
  const float* bih1b = (const float*)d_in[15];
  const float* bhh1b = (const float*)d_in[16];
  const float* fcw   = (const float*)d_in[17];
  const float* fcb   = (const float*)d_in[18];
  float* out = (float*)d_out;

  int slices = (int)(ws_size / (size_t)(H0_SLICE * 2));
  int grid = slices < 1 ? 1 : (slices > MAXGRID ? MAXGRID : slices);
  if (grid > NGRP) grid = NGRP;

  lstm_fc_kernel<<<dim3(grid), dim3(NTHR), 0, stream>>>(x,
      Wih0f, Whh0f, bih0f, bhh0f, Wih0b, Whh0b, bih0b, bhh0b,
      Wih1f, Whh1f, bih1f, bhh1f, Wih1b, Whh1b, bih1b, bhh1b,
      fcw, fcb, out, (_Float16*)d_ws);
}